// Round 15
// baseline (281.059 us; speedup 1.0000x reference)
//
#include <hip/hip_runtime.h>
#include <hip/hip_bf16.h>

typedef float f32x4 __attribute__((ext_vector_type(4)));
typedef short short8 __attribute__((ext_vector_type(8)));
typedef __bf16 bf16x8 __attribute__((ext_vector_type(8)));

#define N_TOT 16384
#define FEATS 256
#define BM 128
#define BK 32
#define KSPLIT 4
#define NSTEPS ((N_TOT / KSPLIT) / BK)   // 128
#define LDSA_BYTES (BM * 128)            // fp32 A tile, 128B rows, 16 KiB
#define LDSB_BYTES (FEATS * 64)          // bf16 B tile,  64B rows, 16 KiB
#define TILE_BYTES (LDSA_BYTES + LDSB_BYTES)

static __device__ __forceinline__ ushort f2bf(float f) {
  union { __hip_bfloat16 b; ushort u; } cv;
  cv.b = __float2bfloat16(f);
  return cv.u;
}
static __device__ __forceinline__ float bf2f(ushort u) {
  union { unsigned int i; float f; } c;
  c.i = ((unsigned int)u) << 16;
  return c.f;
}
static __device__ __forceinline__ short8 cvt8s(float4 a, float4 b) {
  short8 r = { (short)f2bf(a.x), (short)f2bf(a.y), (short)f2bf(a.z), (short)f2bf(a.w),
               (short)f2bf(b.x), (short)f2bf(b.y), (short)f2bf(b.z), (short)f2bf(b.w) };
  return r;
}
// aux CPol: bit1 = NT. A-stream NT=2 (zero reuse -> skip L2 alloc; r12: -7%).
template <int AUX>
static __device__ __forceinline__ void gload_lds16(const void* g, void* l) {
  __builtin_amdgcn_global_load_lds((const __attribute__((address_space(1))) unsigned int*)g,
                                   (__attribute__((address_space(3))) unsigned int*)l,
                                   16, 0, AUX);
}

// ---- K0: F2T[o][m] = (features @ W^T)^T in bf16 (associativity fusion)
__global__ __launch_bounds__(64) void k_f2t(const float* __restrict__ feat,
                                            const float* __restrict__ W,
                                            ushort* __restrict__ F2T) {
  const int lane = threadIdx.x;
  const int rsel = lane & 15, kg = lane >> 4;
  const int mb = blockIdx.x >> 1;
  const int o0 = (blockIdx.x & 1) * 128;
  const int m0 = mb * 16;

  f32x4 acc[8] = {};
#pragma unroll
  for (int ks = 0; ks < 8; ++ks) {
    const int k0 = ks * 32 + kg * 8;
    const float4 fa0 = *(const float4*)(feat + (size_t)(m0 + rsel) * FEATS + k0);
    const float4 fa1 = *(const float4*)(feat + (size_t)(m0 + rsel) * FEATS + k0 + 4);
    const short8 af = cvt8s(fa0, fa1);
#pragma unroll
    for (int of = 0; of < 8; ++of) {
      const float4 wb0 = *(const float4*)(W + (size_t)(o0 + of * 16 + rsel) * FEATS + k0);
      const float4 wb1 = *(const float4*)(W + (size_t)(o0 + of * 16 + rsel) * FEATS + k0 + 4);
      acc[of] = __builtin_amdgcn_mfma_f32_16x16x32_bf16(
          __builtin_bit_cast(bf16x8, af), __builtin_bit_cast(bf16x8, cvt8s(wb0, wb1)),
          acc[of], 0, 0, 0);
    }
  }
#pragma unroll
  for (int of = 0; of < 8; ++of) {
    ushort4 ov = { f2bf(acc[of][0]), f2bf(acc[of][1]), f2bf(acc[of][2]), f2bf(acc[of][3]) };
    *(ushort4*)(F2T + (size_t)(o0 + of * 16 + rsel) * N_TOT + m0 + kg * 4) = ov;
  }
}

// ---- K1: BYTE-IDENTICAL to round 12's champion (263us): BM=128, depth-2,
// 2 barriers/step, vmcnt(4), NT on A. Only the B pointer name changed (F2T).
__global__ __launch_bounds__(512, 4) void k_gemm1(const float* __restrict__ graph,
                                                  const ushort* __restrict__ F2T,
                                                  ushort* __restrict__ parts) {
  __shared__ char lds[2][TILE_BYTES];   // 64 KiB
  const int tid = threadIdx.x;
  const int lane = tid & 63, w = tid >> 6;
  const int wm = w >> 2, wn = w & 3;

  const int b = blockIdx.x;             // 512 blocks; b&7 = XCD (round-robin)
  const int xcd = b & 7;
  const int kb = xcd >> 1;
  const int mi = (b >> 3) | ((xcd & 1) << 6);
  const size_t m0 = (size_t)mi * BM;
  const int kbase = kb * (N_TOT / KSPLIT);
  const int ph = (b * 53) & (NSTEPS - 1);

  auto stage = [&](int bf, int t) {
    const int k0 = kbase + t * BK;
    char* ldsA = &lds[bf][0];
    char* ldsB = &lds[bf][LDSA_BYTES];
#pragma unroll
    for (int j = 0; j < 2; ++j) {                    // A: 8 fp32 rows per instr, NT
      const int r0 = w * 16 + j * 8;
      const int row = r0 + (lane >> 3);
      const int c = (lane & 7) ^ (row & 7);
      gload_lds16<2>(graph + (m0 + row) * (size_t)N_TOT + k0 + c * 4, ldsA + r0 * 128);
    }
#pragma unroll
    for (int j = 0; j < 2; ++j) {                    // B: 16 bf16 rows per instr
      const int r0 = w * 32 + j * 16;
      const int row = r0 + (lane >> 2);
      const int c = (lane & 3) ^ (row & 3);
      gload_lds16<0>(F2T + (size_t)row * N_TOT + k0 + c * 8, ldsB + r0 * 64);
    }
  };

  f32x4 acc[4][4] = {};
  const int rsel = lane & 15;
  const int kg = lane >> 4;

  auto compute = [&](int bf) {
    const char* Ab = &lds[bf][0];
    const char* Bb = &lds[bf][LDSA_BYTES];
    short8 bfr[4];
#pragma unroll
    for (int nf = 0; nf < 4; ++nf) {
      const int row = wn * 64 + nf * 16 + rsel;
      const int c = kg ^ (row & 3);
      bfr[nf] = *(const short8*)(Bb + row * 64 + c * 16);
    }
#pragma unroll
    for (int mf = 0; mf < 4; ++mf) {
      const int row = wm * 64 + mf * 16 + rsel;
      const int cb = (row & 7);
      const float4 a0 = *(const float4*)(Ab + row * 128 + ((kg * 2) ^ cb) * 16);
      const float4 a1 = *(const float4*)(Ab + row * 128 + ((kg * 2 + 1) ^ cb) * 16);
      const short8 af = cvt8s(a0, a1);
#pragma unroll
      for (int nf = 0; nf < 4; ++nf)
        acc[mf][nf] = __builtin_amdgcn_mfma_f32_16x16x32_bf16(
            __builtin_bit_cast(bf16x8, af), __builtin_bit_cast(bf16x8, bfr[nf]),
            acc[mf][nf], 0, 0, 0);
    }
  };

  stage(0, ph);
  stage(1, (ph + 1) & (NSTEPS - 1));

  for (int s = 0; s < NSTEPS - 2; ++s) {
    asm volatile("s_waitcnt vmcnt(4)" ::: "memory");
    __builtin_amdgcn_s_barrier();
    __builtin_amdgcn_sched_barrier(0);
    compute(s & 1);
    __builtin_amdgcn_s_barrier();
    stage(s & 1, (s + 2 + ph) & (NSTEPS - 1));
  }
  asm volatile("s_waitcnt vmcnt(4)" ::: "memory");
  __builtin_amdgcn_s_barrier();
  __builtin_amdgcn_sched_barrier(0);
  compute((NSTEPS - 2) & 1);
  asm volatile("s_waitcnt vmcnt(0)" ::: "memory");
  __builtin_amdgcn_s_barrier();
  __builtin_amdgcn_sched_barrier(0);
  compute((NSTEPS - 1) & 1);

  // epilogue: bf16 partial store. C/D: col=lane&15, row=(lane>>4)*4+j
  ushort* p = parts + (size_t)kb * N_TOT * FEATS;
#pragma unroll
  for (int mf = 0; mf < 4; ++mf)
#pragma unroll
    for (int nf = 0; nf < 4; ++nf)
#pragma unroll
      for (int j = 0; j < 4; ++j) {
        const int row = wm * 64 + mf * 16 + ((lane >> 4) << 2) + j;
        const int col = wn * 64 + nf * 16 + (lane & 15);
        p[(m0 + row) * FEATS + col] = f2bf(acc[mf][nf][j]);
      }
}

// ---- K2: out = relu(sum_kb parts[kb] + b)  (streaming reduce)
__global__ __launch_bounds__(256) void k_reduce(const ushort* __restrict__ parts,
                                                const float* __restrict__ bias,
                                                float* __restrict__ out) {
  const size_t base = ((size_t)blockIdx.x * 256 + threadIdx.x) * 8;
  const int o0 = (int)(base & (FEATS - 1));
  float s[8] = {0, 0, 0, 0, 0, 0, 0, 0};
#pragma unroll
  for (int p = 0; p < KSPLIT; ++p) {
    const short8 v = *(const short8*)(parts + (size_t)p * N_TOT * FEATS + base);
#pragma unroll
    for (int j = 0; j < 8; ++j) s[j] += bf2f((ushort)v[j]);
  }
  const float4 b0 = *(const float4*)(bias + o0);
  const float4 b1 = *(const float4*)(bias + o0 + 4);
  float4 r0 = { fmaxf(s[0] + b0.x, 0.f), fmaxf(s[1] + b0.y, 0.f),
                fmaxf(s[2] + b0.z, 0.f), fmaxf(s[3] + b0.w, 0.f) };
  float4 r1 = { fmaxf(s[4] + b1.x, 0.f), fmaxf(s[5] + b1.y, 0.f),
                fmaxf(s[6] + b1.z, 0.f), fmaxf(s[7] + b1.w, 0.f) };
  *(float4*)(out + base) = r0;
  *(float4*)(out + base + 4) = r1;
}

extern "C" void kernel_launch(void* const* d_in, const int* in_sizes, int n_in,
                              void* d_out, int out_size, void* d_ws, size_t ws_size,
                              hipStream_t stream) {
  const float* graph = (const float*)d_in[0];
  const float* feat  = (const float*)d_in[1];
  const float* W     = (const float*)d_in[2];
  const float* bias  = (const float*)d_in[3];
  float* out = (float*)d_out;

  char* ws = (char*)d_ws;
  ushort* F2T   = (ushort*)ws;                                 // 8 MiB
  ushort* parts = (ushort*)(ws + (size_t)8 * 1024 * 1024);     // 32 MiB

  k_f2t<<<dim3(2048), 64, 0, stream>>>(feat, W, F2T);
  k_gemm1<<<dim3((N_TOT / BM) * KSPLIT), 512, 0, stream>>>(graph, F2T, parts);
  k_reduce<<<dim3(N_TOT * FEATS / 8 / 256), 256, 0, stream>>>(parts, bias, out);
}